// Round 2
// baseline (299.348 us; speedup 1.0000x reference)
//
#include <hip/hip_runtime.h>

#define B_ 4
#define C_ 16
#define L_ 512
#define H_ 1024
// rows per half = B*C*L = 32768 = 2^15

// Kernel 1: one wave per 4 consecutive rows of ONE half (no runtime array
// selection -> everything stays in VGPRs). Row dot with v-half, 64-lane
// butterfly reduce, transposed scatter of the 4 scalars by lane 0.
// se layout: se[half][b][l][c]  (so kernel 2 reads float4 over c)
__global__ __launch_bounds__(256) void dot_kernel(const float4* __restrict__ start,
                                                  const float4* __restrict__ endp,
                                                  const float4* __restrict__ v,
                                                  float* __restrict__ se) {
    const int lane = threadIdx.x & 63;
    const int wv   = (blockIdx.x << 2) | (threadIdx.x >> 6);   // 0..16383
    const int half = wv >> 13;                                 // 8192 waves/half
    const int r0   = (wv & 8191) << 2;                         // 4 rows per wave

    const float4* __restrict__ base = half ? endp : start;     // scalar select, once
    const float4* __restrict__ vh   = v + half * (H_ / 4);

    float4 vf[4];
#pragma unroll
    for (int k = 0; k < 4; ++k) vf[k] = vh[k * 64 + lane];

    // 16 independent loads, all in flight together (16 KB/wave).
    float4 x[4][4];
#pragma unroll
    for (int r = 0; r < 4; ++r) {
        const float4* in = base + (size_t)(r0 + r) * (H_ / 4);
#pragma unroll
        for (int k = 0; k < 4; ++k) x[r][k] = in[k * 64 + lane];
    }

    float acc[4];
#pragma unroll
    for (int r = 0; r < 4; ++r) {
        float a = 0.f;
#pragma unroll
        for (int k = 0; k < 4; ++k)
            a += x[r][k].x * vf[k].x + x[r][k].y * vf[k].y +
                 x[r][k].z * vf[k].z + x[r][k].w * vf[k].w;
        acc[r] = a;
    }

    // 4 independent butterfly chains (ILP across r).
#pragma unroll
    for (int m = 32; m > 0; m >>= 1) {
#pragma unroll
        for (int r = 0; r < 4; ++r) acc[r] += __shfl_xor(acc[r], m, 64);
    }

    if (lane == 0) {
        // rows r0..r0+3 share b,c; l = l0..l0+3 (r0 % 4 == 0, no 512-crossing)
        const int b  = r0 >> 13;               // r0 / (C*L)
        const int c  = (r0 >> 9) & (C_ - 1);   // (r0 / L) % C
        const int l0 = r0 & (L_ - 1);
        float* p = se + (half << 15) + (((b << 9) | l0) << 4) + c;
#pragma unroll
        for (int r = 0; r < 4; ++r) p[r << 4] = acc[r];
    }
}

// Kernel 2: one block per (b,i). out[b,i,j,c] = s[b,i,c] + e[b,j,c].
// s is 4 uniform float4 (each thread keeps its cq slice), e streams from L2,
// stores are 32 KB contiguous per block.
__global__ __launch_bounds__(256) void outer_kernel(const float4* __restrict__ se4,
                                                    float4* __restrict__ out4) {
    const int bi  = blockIdx.x;                // b*L + i
    const int b   = bi >> 9;
    const int tid = threadIdx.x;

    const float4 s = se4[(bi << 2) | (tid & 3)];
    const float4* __restrict__ e = se4 + (B_ * L_ * 4) + (b << 11);  // e[b,0,0]
    float4* __restrict__ o = out4 + (size_t)bi * (L_ * C_ / 4);      // 2048 float4

    float4 ev[8];
#pragma unroll
    for (int it = 0; it < 8; ++it) ev[it] = e[it * 256 + tid];
#pragma unroll
    for (int it = 0; it < 8; ++it) {
        float4 r;
        r.x = s.x + ev[it].x;
        r.y = s.y + ev[it].y;
        r.z = s.z + ev[it].z;
        r.w = s.w + ev[it].w;
        o[it * 256 + tid] = r;
    }
}

extern "C" void kernel_launch(void* const* d_in, const int* in_sizes, int n_in,
                              void* d_out, int out_size, void* d_ws, size_t ws_size,
                              hipStream_t stream) {
    const float4* start = (const float4*)d_in[0];
    const float4* endp  = (const float4*)d_in[1];
    const float4* v     = (const float4*)d_in[2];
    float*        se    = (float*)d_ws;      // 2*B*L*C floats = 256 KB
    float4*       out4  = (float4*)d_out;

    // 4096 blocks x 4 waves = 16384 waves x 4 rows = 65536 rows, static.
    dot_kernel<<<4096, 256, 0, stream>>>(start, endp, v, se);

    // One block per (b,i): 2048 blocks.
    outer_kernel<<<B_ * L_, 256, 0, stream>>>((const float4*)se, out4);
}

// Round 4
// 271.180 us; speedup vs baseline: 1.1039x; 1.1039x over previous
//
#include <hip/hip_runtime.h>

#define B_ 4
#define C_ 16
#define L_ 512
#define H_ 1024
// rows per half = B*C*L = 32768 = 2^15

typedef float f4 __attribute__((ext_vector_type(4)));  // nontemporal-builtin-friendly

// Kernel 1: one wave per 4 consecutive rows of ONE half. All 16 row-loads are
// issued nontemporally BEFORE a sched_barrier(0) fence so 16 KB/wave stays in
// flight (MLP), then FMA + 64-lane butterfly reduce, transposed scatter.
// se layout: se[half][b][l][c] (so kernel 2 reads f4 over c).
__global__ __launch_bounds__(256) void dot_kernel(const f4* __restrict__ start,
                                                  const f4* __restrict__ endp,
                                                  const f4* __restrict__ v,
                                                  float* __restrict__ se) {
    const int lane = threadIdx.x & 63;
    const int wv   = (blockIdx.x << 2) | (threadIdx.x >> 6);   // 0..16383
    const int half = wv >> 13;                                 // 8192 waves/half
    const int r0   = (wv & 8191) << 2;                         // 4 rows per wave

    const f4* __restrict__ base = half ? endp : start;         // scalar select
    const f4* __restrict__ vh   = v + half * (H_ / 4);

    f4 vf[4];
#pragma unroll
    for (int k = 0; k < 4; ++k) vf[k] = vh[k * 64 + lane];

    // Issue ALL 16 global loads (read-once data -> nontemporal); fence keeps
    // consumers below: 64 live dest VGPRs = 16-deep MLP per wave.
    const f4* in = base + (size_t)r0 * (H_ / 4);
    f4 x[4][4];
#pragma unroll
    for (int r = 0; r < 4; ++r)
#pragma unroll
        for (int k = 0; k < 4; ++k)
            x[r][k] = __builtin_nontemporal_load(in + r * (H_ / 4) + k * 64 + lane);

    __builtin_amdgcn_sched_barrier(0);

    float acc[4];
#pragma unroll
    for (int r = 0; r < 4; ++r) {
        float a = 0.f;
#pragma unroll
        for (int k = 0; k < 4; ++k)
            a += x[r][k].x * vf[k].x + x[r][k].y * vf[k].y +
                 x[r][k].z * vf[k].z + x[r][k].w * vf[k].w;
        acc[r] = a;
    }

#pragma unroll
    for (int m = 32; m > 0; m >>= 1) {
#pragma unroll
        for (int r = 0; r < 4; ++r) acc[r] += __shfl_xor(acc[r], m, 64);
    }

    if (lane == 0) {
        const int b  = r0 >> 13;
        const int c  = (r0 >> 9) & (C_ - 1);
        const int l0 = r0 & (L_ - 1);
        float* p = se + (half << 15) + (((b << 9) | l0) << 4) + c;
#pragma unroll
        for (int r = 0; r < 4; ++r) p[r << 4] = acc[r];
    }
}

// Kernel 2: one block per (b,i). out[b,i,j,c] = s[b,i,c] + e[b,j,c].
// e streams from L2 (se is 256 KB, cache-resident); stores are nontemporal
// 32 KB contiguous per block (output never re-read by kernels).
__global__ __launch_bounds__(256) void outer_kernel(const f4* __restrict__ se4,
                                                    f4* __restrict__ out4) {
    const int bi  = blockIdx.x;                // b*L + i
    const int b   = bi >> 9;
    const int tid = threadIdx.x;

    const f4 s = se4[(bi << 2) | (tid & 3)];
    const f4* __restrict__ e = se4 + (B_ * L_ * 4) + (b << 11);
    f4* __restrict__ o = out4 + (size_t)bi * (L_ * C_ / 4);

    f4 ev[8];
#pragma unroll
    for (int it = 0; it < 8; ++it) ev[it] = e[it * 256 + tid];
#pragma unroll
    for (int it = 0; it < 8; ++it) {
        f4 r = s + ev[it];
        __builtin_nontemporal_store(r, o + it * 256 + tid);
    }
}

extern "C" void kernel_launch(void* const* d_in, const int* in_sizes, int n_in,
                              void* d_out, int out_size, void* d_ws, size_t ws_size,
                              hipStream_t stream) {
    const f4* start = (const f4*)d_in[0];
    const f4* endp  = (const f4*)d_in[1];
    const f4* v     = (const f4*)d_in[2];
    float*    se    = (float*)d_ws;      // 2*B*L*C floats = 256 KB
    f4*       out4  = (f4*)d_out;

    dot_kernel<<<4096, 256, 0, stream>>>(start, endp, v, se);
    outer_kernel<<<B_ * L_, 256, 0, stream>>>((const f4*)se, out4);
}